// Round 5
// baseline (878.293 us; speedup 1.0000x reference)
//
#include <hip/hip_runtime.h>

#define NN 100000
#define NE 1200000
#define NG 2048
#define D 64
#define C 2

#define SB 512
#define NB ((NN + SB - 1) / SB)   // 196 scan blocks

__device__ __forceinline__ int atomAddI(int* p, int v) {
    return __hip_atomic_fetch_add(p, v, __ATOMIC_RELAXED, __HIP_MEMORY_SCOPE_AGENT);
}

// ---------------- CSR build ----------------
__global__ void k_hist(const int* __restrict__ dst, int* __restrict__ deg) {
    int e = blockIdx.x * blockDim.x + threadIdx.x;
    if (e < NE) atomAddI(&deg[dst[e]], 1);
}

__global__ void k_scan1(const int* __restrict__ deg, int* __restrict__ locx,
                        int* __restrict__ bsum) {
    __shared__ int sm[256];
    int t = threadIdx.x;
    int i0 = blockIdx.x * SB + 2 * t;
    int d0 = (i0 < NN) ? deg[i0] : 0;
    int d1 = (i0 + 1 < NN) ? deg[i0 + 1] : 0;
    int s = d0 + d1;
    sm[t] = s;
    __syncthreads();
    for (int off = 1; off < 256; off <<= 1) {
        int v = (t >= off) ? sm[t - off] : 0;
        __syncthreads();
        sm[t] += v;
        __syncthreads();
    }
    int ex = sm[t] - s;
    if (i0 < NN) locx[i0] = ex;
    if (i0 + 1 < NN) locx[i0 + 1] = ex + d0;
    if (t == 255) bsum[blockIdx.x] = sm[255];
}

__global__ void k_scan2(const int* __restrict__ bsum, int* __restrict__ boff) {
    __shared__ int sm[NB];
    int t = threadIdx.x;
    if (t < NB) sm[t] = bsum[t];
    __syncthreads();
    if (t == 0) {
        int run = 0;
        for (int i = 0; i < NB; ++i) { int v = sm[i]; sm[i] = run; run += v; }
    }
    __syncthreads();
    if (t < NB) boff[t] = sm[t];
}

__global__ void k_scan3(const int* __restrict__ locx, const int* __restrict__ boff,
                        int* __restrict__ start, int* __restrict__ cursor) {
    int i = blockIdx.x * SB + threadIdx.x;
    if (i < NN) {
        int v = locx[i] + boff[blockIdx.x];
        start[i] = v;
        cursor[i] = v;
    }
    if (i == 0) start[NN] = NE;
}

__global__ void k_build(const int* __restrict__ src, const int* __restrict__ dst,
                        int* __restrict__ cursor, int* __restrict__ csr_src) {
    int e = blockIdx.x * blockDim.x + threadIdx.x;
    if (e < NE) {
        int pos = atomAddI(&cursor[dst[e]], 1);
        csr_src[pos] = src[e];
    }
}

// ---------------- embedding -> transposed slabs T0[c][n][8] ----------------
__global__ void k_embedT(const int* __restrict__ x, const float* __restrict__ emb,
                         float* __restrict__ T0) {
    int tid = blockIdx.x * blockDim.x + threadIdx.x;
    if (tid >= NN * 64) return;
    int c = tid / (NN * 8);
    int r = tid % (NN * 8);
    int n = r >> 3, f = r & 7;
    T0[tid] = emb[(size_t)x[n] * 64 + c * 8 + f];
}

// ---------------- chunked CSR aggregate, chunk-per-XCD ----------------
// 8000 blocks; chunk = blockIdx.x & 7 matches the round-robin block->XCD
// mapping, so each 3.2 MB slab is filled into exactly ONE per-XCD L2.
// Cooperative prefetch: each block streams its 3.2 KB slice of the slab.
__global__ void k_agg8(const int* __restrict__ start, const int* __restrict__ csr,
                       const float* __restrict__ gT, float* __restrict__ aggT) {
    int lane = threadIdx.x & 63;
    int wave = threadIdx.x >> 6;
    int c  = blockIdx.x & 7;
    int nb = blockIdx.x >> 3;            // 0..999
    const float* gsl = gT + (size_t)c * NN * 8;
    float* asl = aggT + (size_t)c * NN * 8;

    // streaming prefetch of this block's slab slice (consumed as *0.0f)
    float pf = 0.f;
    if (threadIdx.x < 200) {
        int i = nb * 200 + threadIdx.x;              // float4 index; 1000*200 = NN*2 exactly
        float4 v = ((const float4*)gsl)[i];
        pf = v.x * 0.0f;
    }

    int f = lane & 7;
    int es = lane >> 3;
    int n0 = nb * 100 + wave * 25;
    for (int j = 0; j < 25; ++j) {
        int n = __builtin_amdgcn_readfirstlane(n0 + j);
        int s0 = start[n], s1 = start[n + 1];
        float acc = pf;
        for (int i0 = s0; i0 < s1; i0 += 8) {
            int e = i0 + es;
            if (e < s1) acc += gsl[(size_t)csr[e] * 8 + f];
        }
        acc += __shfl_xor(acc, 8, 64);
        acc += __shfl_xor(acc, 16, 64);
        acc += __shfl_xor(acc, 32, 64);
        if (lane < 8) asl[(size_t)n * 8 + lane] = acc;
    }
}

// ---------------- SAGE linear (+ReLU), LDS-staged ----------------
// Block = 64 nodes. Stage agg+root rows per-slab with coalesced float4 loads
// (waves 0-1: agg, waves 2-3: root), then register-resident-W matvec reading
// LDS broadcasts. outSlab may alias rootT: each block owns its 64 rows and
// all root reads precede stores.
__global__ void k_lin(const int* __restrict__ start, const float* __restrict__ aggT,
                      const float* rootT,
                      const float4* __restrict__ Wl, const float* __restrict__ bl,
                      const float4* __restrict__ Wr,
                      float* outRow, float* outSlab) {
    __shared__ float sA[64][68];
    __shared__ float sR[64][68];
    int tid = threadIdx.x;
    int lane = tid & 63, wave = tid >> 6;
    int n0 = blockIdx.x * 64;

    {
        int arr = tid >> 7;          // 0: agg, 1: root
        int idx = tid & 127;
        int nl = idx >> 1;           // local node 0..63
        int f4 = idx & 1;            // float4 within 8-float row
        const float* srcp = arr ? rootT : aggT;
        float* dstp = arr ? &sR[0][0] : &sA[0][0];
        int n = n0 + nl;
        if (n >= NN) n = NN - 1;     // clamp (tail block); compute is guarded
#pragma unroll
        for (int c = 0; c < 8; ++c) {
            float4 v = ((const float4*)(srcp + (size_t)c * NN * 8 + (size_t)n * 8))[f4];
            *(float4*)(dstp + nl * 68 + c * 8 + f4 * 4) = v;
        }
    }
    __syncthreads();

    float4 wl[16], wr[16];
#pragma unroll
    for (int i = 0; i < 16; ++i) {
        wl[i] = Wl[lane * 16 + i];
        wr[i] = Wr[lane * 16 + i];
    }
    float bias = bl[lane];

    for (int j = 0; j < 16; ++j) {
        int nl = wave * 16 + j;
        int n = n0 + nl;
        if (n >= NN) break;
        int s0 = start[n], s1 = start[n + 1];
        float inv = 1.0f / (float)max(s1 - s0, 1);
        const float4* ap = (const float4*)&sA[nl][0];
        const float4* rp = (const float4*)&sR[nl][0];
        float a = 0.f, r = 0.f;
#pragma unroll
        for (int k = 0; k < 16; ++k) {
            float4 a4 = ap[k], h4 = rp[k];
            a += a4.x * wl[k].x + a4.y * wl[k].y + a4.z * wl[k].z + a4.w * wl[k].w;
            r += h4.x * wr[k].x + h4.y * wr[k].y + h4.z * wr[k].z + h4.w * wr[k].w;
        }
        float v = fmaxf(a * inv + bias + r, 0.f);
        if (outRow)  outRow[(size_t)n * D + lane] = v;
        if (outSlab) outSlab[(size_t)(lane >> 3) * NN * 8 + (size_t)n * 8 + (lane & 7)] = v;
    }
}

// ---------------- readout ----------------
__global__ void k_bounds(const int* __restrict__ batch, int* __restrict__ gs) {
    int n = blockIdx.x * blockDim.x + threadIdx.x;
    if (n >= NN) return;
    int b = batch[n];
    if (n == 0) {
        for (int g = 0; g <= b; ++g) gs[g] = 0;
    } else {
        int bp = batch[n - 1];
        for (int g = bp + 1; g <= b; ++g) gs[g] = n;
    }
    if (n == NN - 1) {
        for (int g = b + 1; g <= NG; ++g) gs[g] = NN;
    }
}

__global__ void k_pool(const int* __restrict__ gs, const float* __restrict__ h,
                       const float* __restrict__ Wout, const float* __restrict__ bout,
                       float* __restrict__ out) {
    int lane = threadIdx.x & 63;
    int wave = threadIdx.x >> 6;
    int g = blockIdx.x * 4 + wave;
    int s0 = gs[g], s1 = gs[g + 1];
    float p = 0.f;
    for (int n = s0; n < s1; ++n) p += h[(size_t)n * D + lane];
    p *= 1.0f / (float)max(s1 - s0, 1);
    float c0 = p * Wout[lane];
    float c1 = p * Wout[D + lane];
#pragma unroll
    for (int off = 32; off > 0; off >>= 1) {
        c0 += __shfl_down(c0, off, 64);
        c1 += __shfl_down(c1, off, 64);
    }
    if (lane == 0) {
        out[g * C + 0] = c0 + bout[0];
        out[g * C + 1] = c1 + bout[1];
    }
}

extern "C" void kernel_launch(void* const* d_in, const int* in_sizes, int n_in,
                              void* d_out, int out_size, void* d_ws, size_t ws_size,
                              hipStream_t stream) {
    const int*   x     = (const int*)d_in[0];
    const int*   src   = (const int*)d_in[1];
    const int*   dst   = src + NE;
    const int*   batch = (const int*)d_in[2];
    const float* emb   = (const float*)d_in[3];
    const float* W1l   = (const float*)d_in[4];
    const float* b1l   = (const float*)d_in[5];
    const float* W1r   = (const float*)d_in[6];
    const float* W2l   = (const float*)d_in[7];
    const float* b2l   = (const float*)d_in[8];
    const float* W2r   = (const float*)d_in[9];
    const float* Wout  = (const float*)d_in[10];
    const float* bout  = (const float*)d_in[11];
    float* out = (float*)d_out;

    float* T0 = (float*)d_ws;                 // NN*64 slabs (gather src / root)
    float* TA = T0 + (size_t)NN * 64;         // NN*64 agg slabs
    float* h2 = TA + (size_t)NN * 64;         // NN*64 row-major (for pool)
    int* deg    = (int*)(h2 + (size_t)NN * 64);
    int* startA = deg + NN;
    int* cursor = startA + NN + 1;
    int* locx   = cursor + NN;
    int* bsum   = locx + NN;
    int* boff   = bsum + NB;
    int* gs     = boff + NB;
    int* csr    = gs + NG + 1;

    hipMemsetAsync(deg, 0, NN * sizeof(int), stream);

    k_hist <<<(NE + 255) / 256, 256, 0, stream>>>(dst, deg);
    k_scan1<<<NB, 256, 0, stream>>>(deg, locx, bsum);
    k_scan2<<<1, 256, 0, stream>>>(bsum, boff);
    k_scan3<<<NB, SB, 0, stream>>>(locx, boff, startA, cursor);
    k_build<<<(NE + 255) / 256, 256, 0, stream>>>(src, dst, cursor, csr);

    k_embedT<<<(NN * 64 + 255) / 256, 256, 0, stream>>>(x, emb, T0);
    k_bounds<<<(NN + 255) / 256, 256, 0, stream>>>(batch, gs);

    // ---- layer 1 ----
    k_agg8<<<8000, 256, 0, stream>>>(startA, csr, T0, TA);
    k_lin <<<(NN + 63) / 64, 256, 0, stream>>>(startA, TA, T0, (const float4*)W1l, b1l,
                                               (const float4*)W1r, nullptr, T0);
    // ---- layer 2 ----
    k_agg8<<<8000, 256, 0, stream>>>(startA, csr, T0, TA);
    k_lin <<<(NN + 63) / 64, 256, 0, stream>>>(startA, TA, T0, (const float4*)W2l, b2l,
                                               (const float4*)W2r, h2, nullptr);

    // ---- readout ----
    k_pool<<<NG / 4, 256, 0, stream>>>(gs, h2, Wout, bout, out);
}

// Round 6
// 670.497 us; speedup vs baseline: 1.3099x; 1.3099x over previous
//
#include <hip/hip_runtime.h>

#define NN 100000
#define NE 1200000
#define NG 2048
#define D 64
#define C 2

#define SB 512
#define NB ((NN + SB - 1) / SB)   // 196 scan blocks

__device__ __forceinline__ int atomAddI(int* p, int v) {
    return __hip_atomic_fetch_add(p, v, __ATOMIC_RELAXED, __HIP_MEMORY_SCOPE_AGENT);
}

// ---------------- CSR build ----------------
__global__ void __launch_bounds__(256) k_hist(const int* __restrict__ dst, int* __restrict__ deg) {
    int e = blockIdx.x * blockDim.x + threadIdx.x;
    if (e < NE) atomAddI(&deg[dst[e]], 1);
}

__global__ void __launch_bounds__(256) k_scan1(const int* __restrict__ deg, int* __restrict__ locx,
                        int* __restrict__ bsum) {
    __shared__ int sm[256];
    int t = threadIdx.x;
    int i0 = blockIdx.x * SB + 2 * t;
    int d0 = (i0 < NN) ? deg[i0] : 0;
    int d1 = (i0 + 1 < NN) ? deg[i0 + 1] : 0;
    int s = d0 + d1;
    sm[t] = s;
    __syncthreads();
    for (int off = 1; off < 256; off <<= 1) {
        int v = (t >= off) ? sm[t - off] : 0;
        __syncthreads();
        sm[t] += v;
        __syncthreads();
    }
    int ex = sm[t] - s;
    if (i0 < NN) locx[i0] = ex;
    if (i0 + 1 < NN) locx[i0 + 1] = ex + d0;
    if (t == 255) bsum[blockIdx.x] = sm[255];
}

__global__ void __launch_bounds__(256) k_scan2(const int* __restrict__ bsum, int* __restrict__ boff) {
    __shared__ int sm[NB];
    int t = threadIdx.x;
    if (t < NB) sm[t] = bsum[t];
    __syncthreads();
    if (t == 0) {
        int run = 0;
        for (int i = 0; i < NB; ++i) { int v = sm[i]; sm[i] = run; run += v; }
    }
    __syncthreads();
    if (t < NB) boff[t] = sm[t];
}

__global__ void __launch_bounds__(512) k_scan3(const int* __restrict__ locx, const int* __restrict__ boff,
                        int* __restrict__ start, int* __restrict__ cursor) {
    int i = blockIdx.x * SB + threadIdx.x;
    if (i < NN) {
        int v = locx[i] + boff[blockIdx.x];
        start[i] = v;
        cursor[i] = v;
    }
    if (i == 0) start[NN] = NE;
}

__global__ void __launch_bounds__(256) k_build(const int* __restrict__ src, const int* __restrict__ dst,
                        int* __restrict__ cursor, int* __restrict__ csr_src) {
    int e = blockIdx.x * blockDim.x + threadIdx.x;
    if (e < NE) {
        int pos = atomAddI(&cursor[dst[e]], 1);
        csr_src[pos] = src[e];
    }
}

// ---------------- embedding -> transposed slabs T0[c][n][8] ----------------
__global__ void __launch_bounds__(256) k_embedT(const int* __restrict__ x, const float* __restrict__ emb,
                         float* __restrict__ T0) {
    int tid = blockIdx.x * blockDim.x + threadIdx.x;
    if (tid >= NN * 64) return;
    int c = tid / (NN * 8);
    int r = tid % (NN * 8);
    int n = r >> 3, f = r & 7;
    T0[tid] = emb[(size_t)x[n] * 64 + c * 8 + f];
}

// ---------------- chunked CSR aggregate, chunk-per-XCD ----------------
__global__ void __launch_bounds__(256) k_agg8(const int* __restrict__ start, const int* __restrict__ csr,
                       const float* __restrict__ gT, float* __restrict__ aggT) {
    int lane = threadIdx.x & 63;
    int wave = threadIdx.x >> 6;
    int c  = blockIdx.x & 7;
    int nb = blockIdx.x >> 3;            // 0..999
    const float* gsl = gT + (size_t)c * NN * 8;
    float* asl = aggT + (size_t)c * NN * 8;

    // streaming prefetch of this block's slab slice (consumed as *0.0f)
    float pf = 0.f;
    if (threadIdx.x < 200) {
        int i = nb * 200 + threadIdx.x;              // 1000*200 float4 = NN*2 exactly
        float4 v = ((const float4*)gsl)[i];
        pf = v.x * 0.0f;
    }

    int f = lane & 7;
    int es = lane >> 3;
    int n0 = nb * 100 + wave * 25;
    for (int j = 0; j < 25; ++j) {
        int n = __builtin_amdgcn_readfirstlane(n0 + j);
        int s0 = start[n], s1 = start[n + 1];
        float acc = pf;
        for (int i0 = s0; i0 < s1; i0 += 8) {
            int e = i0 + es;
            if (e < s1) acc += gsl[(size_t)csr[e] * 8 + f];
        }
        acc += __shfl_xor(acc, 8, 64);
        acc += __shfl_xor(acc, 16, 64);
        acc += __shfl_xor(acc, 32, 64);
        if (lane < 8) asl[(size_t)n * 8 + lane] = acc;
    }
}

// ---------------- SAGE linear (+ReLU), LDS-staged, W in registers ----------------
__global__ void __launch_bounds__(256) k_lin(const int* __restrict__ start, const float* __restrict__ aggT,
                      const float* rootT,
                      const float4* __restrict__ Wl, const float* __restrict__ bl,
                      const float4* __restrict__ Wr,
                      float* outRow, float* outSlab) {
    __shared__ float sA[64][68];
    __shared__ float sR[64][68];
    int tid = threadIdx.x;
    int lane = tid & 63, wave = tid >> 6;
    int n0 = blockIdx.x * 64;

    {
        int arr = tid >> 7;          // 0: agg, 1: root
        int idx = tid & 127;
        int nl = idx >> 1;           // local node 0..63
        int f4 = idx & 1;            // float4 within 8-float row
        const float* srcp = arr ? rootT : aggT;
        float* dstp = arr ? &sR[0][0] : &sA[0][0];
        int n = n0 + nl;
        if (n >= NN) n = NN - 1;     // clamp (tail block); compute is guarded
#pragma unroll
        for (int c = 0; c < 8; ++c) {
            float4 v = ((const float4*)(srcp + (size_t)c * NN * 8 + (size_t)n * 8))[f4];
            *(float4*)(dstp + nl * 68 + c * 8 + f4 * 4) = v;
        }
    }
    __syncthreads();

    float4 wl[16], wr[16];
#pragma unroll
    for (int i = 0; i < 16; ++i) {
        wl[i] = Wl[lane * 16 + i];
        wr[i] = Wr[lane * 16 + i];
    }
    float bias = bl[lane];

    for (int j = 0; j < 16; ++j) {
        int nl = wave * 16 + j;
        int n = n0 + nl;
        if (n >= NN) break;
        int s0 = start[n], s1 = start[n + 1];
        float inv = 1.0f / (float)max(s1 - s0, 1);
        const float4* ap = (const float4*)&sA[nl][0];
        const float4* rp = (const float4*)&sR[nl][0];
        float a = 0.f, r = 0.f;
#pragma unroll
        for (int k = 0; k < 16; ++k) {
            float4 a4 = ap[k], h4 = rp[k];
            a += a4.x * wl[k].x + a4.y * wl[k].y + a4.z * wl[k].z + a4.w * wl[k].w;
            r += h4.x * wr[k].x + h4.y * wr[k].y + h4.z * wr[k].z + h4.w * wr[k].w;
        }
        float v = fmaxf(a * inv + bias + r, 0.f);
        if (outRow)  outRow[(size_t)n * D + lane] = v;
        if (outSlab) outSlab[(size_t)(lane >> 3) * NN * 8 + (size_t)n * 8 + (lane & 7)] = v;
    }
}

// ---------------- readout ----------------
__global__ void __launch_bounds__(256) k_bounds(const int* __restrict__ batch, int* __restrict__ gs) {
    int n = blockIdx.x * blockDim.x + threadIdx.x;
    if (n >= NN) return;
    int b = batch[n];
    if (n == 0) {
        for (int g = 0; g <= b; ++g) gs[g] = 0;
    } else {
        int bp = batch[n - 1];
        for (int g = bp + 1; g <= b; ++g) gs[g] = n;
    }
    if (n == NN - 1) {
        for (int g = b + 1; g <= NG; ++g) gs[g] = NN;
    }
}

__global__ void __launch_bounds__(256) k_pool(const int* __restrict__ gs, const float* __restrict__ h,
                       const float* __restrict__ Wout, const float* __restrict__ bout,
                       float* __restrict__ out) {
    int lane = threadIdx.x & 63;
    int wave = threadIdx.x >> 6;
    int g = blockIdx.x * 4 + wave;
    int s0 = gs[g], s1 = gs[g + 1];
    float p = 0.f;
    for (int n = s0; n < s1; ++n) p += h[(size_t)n * D + lane];
    p *= 1.0f / (float)max(s1 - s0, 1);
    float c0 = p * Wout[lane];
    float c1 = p * Wout[D + lane];
#pragma unroll
    for (int off = 32; off > 0; off >>= 1) {
        c0 += __shfl_down(c0, off, 64);
        c1 += __shfl_down(c1, off, 64);
    }
    if (lane == 0) {
        out[g * C + 0] = c0 + bout[0];
        out[g * C + 1] = c1 + bout[1];
    }
}

extern "C" void kernel_launch(void* const* d_in, const int* in_sizes, int n_in,
                              void* d_out, int out_size, void* d_ws, size_t ws_size,
                              hipStream_t stream) {
    const int*   x     = (const int*)d_in[0];
    const int*   src   = (const int*)d_in[1];
    const int*   dst   = src + NE;
    const int*   batch = (const int*)d_in[2];
    const float* emb   = (const float*)d_in[3];
    const float* W1l   = (const float*)d_in[4];
    const float* b1l   = (const float*)d_in[5];
    const float* W1r   = (const float*)d_in[6];
    const float* W2l   = (const float*)d_in[7];
    const float* b2l   = (const float*)d_in[8];
    const float* W2r   = (const float*)d_in[9];
    const float* Wout  = (const float*)d_in[10];
    const float* bout  = (const float*)d_in[11];
    float* out = (float*)d_out;

    float* T0 = (float*)d_ws;                 // NN*64 slabs (gather src / root)
    float* TA = T0 + (size_t)NN * 64;         // NN*64 agg slabs
    float* h2 = TA + (size_t)NN * 64;         // NN*64 row-major (for pool)
    int* deg    = (int*)(h2 + (size_t)NN * 64);
    int* startA = deg + NN;
    int* cursor = startA + NN + 1;
    int* locx   = cursor + NN;
    int* bsum   = locx + NN;
    int* boff   = bsum + NB;
    int* gs     = boff + NB;
    int* csr    = gs + NG + 1;

    hipMemsetAsync(deg, 0, NN * sizeof(int), stream);

    k_hist <<<(NE + 255) / 256, 256, 0, stream>>>(dst, deg);
    k_scan1<<<NB, 256, 0, stream>>>(deg, locx, bsum);
    k_scan2<<<1, 256, 0, stream>>>(bsum, boff);
    k_scan3<<<NB, SB, 0, stream>>>(locx, boff, startA, cursor);
    k_build<<<(NE + 255) / 256, 256, 0, stream>>>(src, dst, cursor, csr);

    k_embedT<<<(NN * 64 + 255) / 256, 256, 0, stream>>>(x, emb, T0);
    k_bounds<<<(NN + 255) / 256, 256, 0, stream>>>(batch, gs);

    // ---- layer 1 ----
    k_agg8<<<8000, 256, 0, stream>>>(startA, csr, T0, TA);
    k_lin <<<(NN + 63) / 64, 256, 0, stream>>>(startA, TA, T0, (const float4*)W1l, b1l,
                                               (const float4*)W1r, nullptr, T0);
    // ---- layer 2 ----
    k_agg8<<<8000, 256, 0, stream>>>(startA, csr, T0, TA);
    k_lin <<<(NN + 63) / 64, 256, 0, stream>>>(startA, TA, T0, (const float4*)W2l, b2l,
                                               (const float4*)W2r, h2, nullptr);

    // ---- readout ----
    k_pool<<<NG / 4, 256, 0, stream>>>(gs, h2, Wout, bout, out);
}